// Round 3
// baseline (126.724 us; speedup 1.0000x reference)
//
#include <hip/hip_runtime.h>
#include <stdint.h>

#define NPTS   65536
#define DDIM   128
#define KCODES 1024

typedef __attribute__((ext_vector_type(8))) _Float16  half8;
typedef __attribute__((ext_vector_type(4))) float     f32x4;
typedef __attribute__((ext_vector_type(4))) int       int4v;
typedef __attribute__((ext_vector_type(2))) _Float16  half2v;

// ---------------- numeric helpers (LOCKED — absmax=0 rounds 2,3,4) ----------------
// 2-limb fp16 Dekker split: x ~= (float)hi + (float)lo / 2048.
__device__ __forceinline__ void split16(float x, _Float16& hi, _Float16& lo) {
  _Float16 h = (__builtin_fabsf(x) < 6.103515625e-05f) ? (_Float16)0.f : (_Float16)x;
  hi = h;
  lo = (_Float16)(__fmul_rn(__fsub_rn(x, (float)h), 2048.f));
}

// numpy pairwise sum of squares for n=128 (bit-exact np.sum(x*x,-1)); serial form.
__device__ __forceinline__ float np_sumsq_128(const float* __restrict__ row) {
  float r[8];
#pragma unroll
  for (int k = 0; k < 8; ++k) r[k] = __fmul_rn(row[k], row[k]);
  for (int i = 8; i < 128; i += 8)
#pragma unroll
    for (int k = 0; k < 8; ++k) r[k] = __fadd_rn(r[k], __fmul_rn(row[i + k], row[i + k]));
  float s01 = __fadd_rn(r[0], r[1]), s23 = __fadd_rn(r[2], r[3]);
  float s45 = __fadd_rn(r[4], r[5]), s67 = __fadd_rn(r[6], r[7]);
  return __fadd_rn(__fadd_rn(s01, s23), __fadd_rn(s45, s67));
}

// global->LDS async copy, 16B/lane. LDS dest = wave-uniform base + lane*16.
__device__ __forceinline__ void async_copy16(const void* g, void* l) {
  auto gp = (const __attribute__((address_space(1))) unsigned int*)(uintptr_t)g;
  auto lp = (__attribute__((address_space(3))) unsigned int*)(unsigned)(uintptr_t)l;
  __builtin_amdgcn_global_load_lds(gp, lp, 16, 0, 0);
}

// ---------------- workspace layout ----------------
constexpr size_t SZ_B   = (size_t)KCODES * DDIM * 2;  // 256 KB per B limb
constexpr size_t OFF_B1 = 0;
constexpr size_t OFF_B2 = SZ_B;
constexpr size_t OFF_C2 = 2 * SZ_B;
constexpr size_t WS_NEED = OFF_C2 + (size_t)KCODES * 4;  // ~516 KB

// ---------------- prep: codebook limbs (XOR-swizzled k-groups) + c2 ----------------
// Element (code,k), kg=k/8, stored at row offset (kg ^ (code&15))*8 + k%8 so that
// linear LDS staging + ds_read_b128 fragment reads are bank-uniform (0 conflicts,
// verified rounds 3-4). c2 via the 8-lane shuffle tree (bit-exact, verified).
__global__ __launch_bounds__(256) void vq_prep_cb(const float* __restrict__ cb,
                                                  _Float16* __restrict__ B1,
                                                  _Float16* __restrict__ B2,
                                                  float* __restrict__ c2) {
  const int w = threadIdx.x >> 6, ln = threadIdx.x & 63;
  const int code = blockIdx.x * 4 + w;  // one wave per code row
  const float2 cv = ((const float2*)(cb + (size_t)code * DDIM))[ln];
  _Float16 h0, l0, h1, l1;
  split16(cv.x, h0, l0); split16(cv.y, h1, l1);
  const int kg = ln >> 2;
  const int o  = 2 * (ln & 3);
  const size_t dst = (size_t)code * DDIM + (size_t)((kg ^ (code & 15)) * 8 + o);
  *(half2v*)(B1 + dst) = (half2v){h0, h1};
  *(half2v*)(B2 + dst) = (half2v){l0, l1};

  if (threadIdx.x < 32) {  // 8 lanes per code, 4 codes
    const int cc = blockIdx.x * 4 + (threadIdx.x >> 3), jj = threadIdx.x & 7;
    const float* row = cb + (size_t)cc * DDIM;
    float e = row[jj];
    float acc = __fmul_rn(e, e);
    for (int i = 1; i < 16; ++i) {
      e = row[i * 8 + jj];
      acc = __fadd_rn(acc, __fmul_rn(e, e));
    }
    float a1 = __fadd_rn(acc, __shfl_xor(acc, 1));
    float a2 = __fadd_rn(a1, __shfl_xor(a1, 2));
    float a4 = __fadd_rn(a2, __shfl_xor(a2, 4));
    if (jj == 0) c2[cc] = a4;
  }
}

// ---------------- main fused z2 + GEMM + argmin ----------------
// ROUND 7 RESHAPE (r5/r6 post-mortem: the 1:2 LDS-read:MFMA ratio is the wall;
// schedule surgery can't fix a ratio problem):
//  - wave tile 64 rows x 32 codes/iter (rf=4): each B fragment feeds 4 MFMAs;
//    with b1 reused across pass1/pass2, 16 ds_read_b128 per 96 MFMA (1:6 vs 1:2).
//  - 4-wave block = 2 row-groups (wr2) x 2 code-parities (wc). Waves split the
//    1024 codes: wc=0 takes codes [u*64, u*64+32), wc=1 takes [u*64+32, u*64+64).
//    Final (v,i)-lexicographic cross-wave merge preserves argmin-first-index.
//  - per-cf blocking with rf=4 gives 4 independent MFMA chains (fixes r6's
//    2-chain ILP stall) and shrinks live acc to 16 VGPR (fits rf=4 in budget).
//  - single buffer per iter holds BOTH limbs of a 64-code tile (32 KB); two
//    buffers double-buffered; ONE __syncthreads per iter; staging issued at
//    iter top gets the full 96-MFMA phase of cover (T3 minimum form, no
//    inline-asm waits -> avoids r6's failure mode).
//  - per-element arithmetic chain UNCHANGED: a1*b2(ks0-3) -> a2*b1(ks0-3) ->
//    *2^-11 -> a1*b1(ks0-3); same fragments/swizzle; epilogue fmaf(dot,-2,z2)
//    is bit-identical to fsub(z2,fmul(2,dot)) because *2 is exact in binary fp.
// LDS: buf[2] 64KB + c2 4KB + z2 512B + merge 1KB = 71168 B; 2 blocks/CU.
__global__ __launch_bounds__(256, 2) void vq_gemm(
    const float* __restrict__ z,
    const unsigned short* __restrict__ B1g, const unsigned short* __restrict__ B2g,
    const float* __restrict__ c2g, int* __restrict__ out) {
  __shared__ alignas(16) char smem[32768 * 2 + 4096 + 512 + 512 + 512];
  float* c2sh = (float*)(smem + 65536);
  float* z2sh = (float*)(smem + 65536 + 4096);
  float* mvx  = (float*)(smem + 65536 + 4096 + 512);
  int*   mix  = (int*)  (smem + 65536 + 4096 + 1024);
  float* Ls   = (float*)smem;  // 32x132 fp32 staging alias (pre-B phase only)

  const int tid = threadIdx.x;
  const int ln = tid & 63, w = tid >> 6;
  const int wr2 = w >> 1, wc = w & 1;
  const int l15 = ln & 15, q = ln >> 4;
  const size_t row0 = (size_t)blockIdx.x * 128;
  const float4* z4 = (const float4*)z;

  // ---- phase 0: z2 for rows row0..row0+127 (np-exact; unchanged) ----
  for (int cc = 0; cc < 4; ++cc) {
#pragma unroll
    for (int j = 0; j < 4; ++j) {
      const int idx = tid + j * 256;  // < 1024 float4 = 32 rows
      float4 v = z4[(row0 + cc * 32) * 32 + idx];
      *(float4*)&Ls[(idx >> 5) * 132 + (idx & 31) * 4] = v;
    }
    __syncthreads();
    {
      const int r = tid >> 3, jj = tid & 7;
      const float* row = &Ls[r * 132];
      float e = row[jj];
      float acc = __fmul_rn(e, e);
      for (int i = 1; i < 16; ++i) {
        e = row[i * 8 + jj];
        acc = __fadd_rn(acc, __fmul_rn(e, e));
      }
      float a1 = __fadd_rn(acc, __shfl_xor(acc, 1));
      float a2 = __fadd_rn(a1, __shfl_xor(a1, 2));
      float a4 = __fadd_rn(a2, __shfl_xor(a2, 4));
      if (jj == 0) z2sh[cc * 32 + r] = a4;
    }
    __syncthreads();  // readers done before next chunk overwrites Ls
  }

  // ---- stage tile 0 (both limbs -> buf0) + c2; A-frag loads overlap drain ----
  {
    unsigned short* nb = (unsigned short*)smem;  // buf0
#pragma unroll
    for (int j = 0; j < 4; ++j) {
      const int s = tid + j * 256;
      async_copy16(B2g + s * 8, nb + s * 8);
    }
#pragma unroll
    for (int j = 0; j < 4; ++j) {
      const int s = tid + j * 256;
      async_copy16(B1g + s * 8, nb + 8192 + s * 8);
    }
    async_copy16(c2g + tid * 4, c2sh + tid * 4);
  }

  // A fragments: 64 rows per wave (rf=4), both limbs -> 128 VGPR
  half8 a1f[4][4], a2f[4][4];
#pragma unroll
  for (int rf = 0; rf < 4; ++rf) {
    const float* zr = z + (row0 + wr2 * 64 + rf * 16 + l15) * DDIM;
#pragma unroll
    for (int ks = 0; ks < 4; ++ks) {
      float tmp[8];
      *(float4*)tmp       = *(const float4*)(zr + ks * 32 + q * 8);
      *(float4*)(tmp + 4) = *(const float4*)(zr + ks * 32 + q * 8 + 4);
      half8 h, l;
#pragma unroll
      for (int e = 0; e < 8; ++e) {
        _Float16 hh, ll;
        split16(tmp[e], hh, ll);
        h[e] = hh; l[e] = ll;
      }
      a1f[rf][ks] = h; a2f[rf][ks] = l;
    }
  }

  float mv[16];
  int mi[16];
#pragma unroll
  for (int i = 0; i < 16; ++i) { mv[i] = 3.0e38f; mi[i] = 0; }

  __syncthreads();  // drain initial staging

  // z2 for this lane's 16 row-slots (loop-invariant)
  float z2r[16];
#pragma unroll
  for (int rf = 0; rf < 4; ++rf)
#pragma unroll
    for (int reg = 0; reg < 4; ++reg)
      z2r[rf * 4 + reg] = z2sh[wr2 * 64 + rf * 16 + q * 4 + reg];

  // ================= main loop: 16 iters, one barrier each =================
  for (int u = 0; u < 16; ++u) {
    const unsigned short* cur = (const unsigned short*)(smem + (u & 1) * 32768);

    // issue next-tile staging FIRST (covered by this iter's 96 MFMAs)
    if (u < 15) {
      unsigned short* nb = (unsigned short*)(smem + ((u + 1) & 1) * 32768);
      const size_t goff = (size_t)(u + 1) * 8192;  // halfs
#pragma unroll
      for (int j = 0; j < 4; ++j) {
        const int s = tid + j * 256;
        async_copy16(B2g + goff + s * 8, nb + s * 8);
      }
#pragma unroll
      for (int j = 0; j < 4; ++j) {
        const int s = tid + j * 256;
        async_copy16(B1g + goff + s * 8, nb + 8192 + s * 8);
      }
    }

    const int c0 = u * 64 + wc * 32;

#pragma unroll
    for (int cf = 0; cf < 2; ++cf) {
      const unsigned short* p = cur + (size_t)(wc * 32 + cf * 16 + l15) * 128;

      f32x4 acc[4];
#pragma unroll
      for (int rf = 0; rf < 4; ++rf) acc[rf] = (f32x4){0.f, 0.f, 0.f, 0.f};

      // ---- pass 0: a1 * b2 (4 independent rf chains) ----
      half8 bb[4];
#pragma unroll
      for (int ks = 0; ks < 4; ++ks)
        bb[ks] = *(const half8*)&p[((ks * 4 + q) ^ l15) * 8];
#pragma unroll
      for (int ks = 0; ks < 4; ++ks)
#pragma unroll
        for (int rf = 0; rf < 4; ++rf)
          acc[rf] = __builtin_amdgcn_mfma_f32_16x16x32_f16(a1f[rf][ks], bb[ks],
                                                           acc[rf], 0, 0, 0);

      // ---- pass 1: a2 * b1 (b1 read once, pinned, reused by pass 2) ----
#pragma unroll
      for (int ks = 0; ks < 4; ++ks) {
        bb[ks] = *(const half8*)&p[8192 + ((ks * 4 + q) ^ l15) * 8];
        asm volatile("" : "+v"(bb[ks]));  // forbid LDS remat for pass 2
      }
#pragma unroll
      for (int ks = 0; ks < 4; ++ks)
#pragma unroll
        for (int rf = 0; rf < 4; ++rf)
          acc[rf] = __builtin_amdgcn_mfma_f32_16x16x32_f16(a2f[rf][ks], bb[ks],
                                                           acc[rf], 0, 0, 0);
      // exact pow-2 descale of the two scaled lo-limb passes
#pragma unroll
      for (int rf = 0; rf < 4; ++rf) acc[rf] = acc[rf] * 4.8828125e-4f;

      // ---- pass 2: a1 * b1 (same fragments, same values, same order) ----
#pragma unroll
      for (int ks = 0; ks < 4; ++ks)
#pragma unroll
        for (int rf = 0; rf < 4; ++rf)
          acc[rf] = __builtin_amdgcn_mfma_f32_16x16x32_f16(a1f[rf][ks], bb[ks],
                                                           acc[rf], 0, 0, 0);

      // ---- epilogue(cf): np-exact fp32 distance -> running argmin.
      //      fmaf(dot,-2,z2) == fsub(z2,fmul(2,dot)) bitwise (x2 exact). ----
      {
        const float c2v = c2sh[c0 + cf * 16 + l15];
        const int idx = c0 + cf * 16 + l15;
#pragma unroll
        for (int rf = 0; rf < 4; ++rf)
#pragma unroll
          for (int reg = 0; reg < 4; ++reg) {
            const int slot = rf * 4 + reg;
            float v = __fadd_rn(__builtin_fmaf(acc[rf][reg], -2.0f, z2r[slot]), c2v);
            if (v < mv[slot]) { mv[slot] = v; mi[slot] = idx; }
          }
      }
    }

    __syncthreads();  // staging(u+1) drained; all waves done reading cur
  }

  // ---- cross-lane argmin over the 16 lanes (same q-group) per slot ----
#pragma unroll
  for (int slot = 0; slot < 16; ++slot) {
    float v = mv[slot];
    int i = mi[slot];
#pragma unroll
    for (int m = 1; m <= 8; m <<= 1) {
      float ov = __shfl_xor(v, m);
      int oi = __shfl_xor(i, m);
      if (ov < v || (ov == v && oi < i)) { v = ov; i = oi; }
    }
    mv[slot] = v; mi[slot] = i;
  }

  // ---- cross-wave merge (wc=1 -> LDS, wc=0 merges; (v,i) lexicographic) ----
  if (l15 == 0 && wc == 1) {
#pragma unroll
    for (int slot = 0; slot < 16; ++slot) {
      const int r = wr2 * 64 + (slot >> 2) * 16 + q * 4 + (slot & 3);
      mvx[r] = mv[slot];
      mix[r] = mi[slot];
    }
  }
  __syncthreads();
  if (l15 == 0 && wc == 0) {
#pragma unroll
    for (int rf = 0; rf < 4; ++rf) {
      int ib[4];
#pragma unroll
      for (int reg = 0; reg < 4; ++reg) {
        const int r = wr2 * 64 + rf * 16 + q * 4 + reg;
        const int slot = rf * 4 + reg;
        float v = mv[slot];
        int i = mi[slot];
        const float ov = mvx[r];
        const int oi = mix[r];
        if (ov < v || (ov == v && oi < i)) { v = ov; i = oi; }
        ib[reg] = i;
      }
      int4v rr = {ib[0], ib[1], ib[2], ib[3]};
      *(int4v*)&out[row0 + wr2 * 64 + rf * 16 + q * 4] = rr;
    }
  }
}

// ---------------- fallback (ws too small): fp64 dots + np fp32 formula ----------------
__global__ __launch_bounds__(256) void vq_fallback(const float* __restrict__ z,
                                                   const float* __restrict__ cb,
                                                   int* __restrict__ out) {
  __shared__ float zs[DDIM];
  __shared__ float z2s;
  __shared__ float bv[256];
  __shared__ int bi[256];
  const int p = blockIdx.x, tid = threadIdx.x;
  if (tid < DDIM) zs[tid] = z[(size_t)p * DDIM + tid];
  __syncthreads();
  if (tid == 0) z2s = np_sumsq_128(zs);
  __syncthreads();
  const float z2p = z2s;
  float best = 3.0e38f;
  int bidx = 0;
  for (int c = tid; c < KCODES; c += 256) {
    const float* cr = cb + (size_t)c * DDIM;
    double acc = 0.0;
#pragma unroll 8
    for (int d = 0; d < DDIM; ++d) acc += (double)zs[d] * (double)cr[d];
    float dfl = (float)acc;
    float c2k = np_sumsq_128(cr);
    float v = __fadd_rn(__fsub_rn(z2p, __fmul_rn(2.f, dfl)), c2k);
    if (v < best) { best = v; bidx = c; }
  }
  bv[tid] = best; bi[tid] = bidx;
  __syncthreads();
  for (int off = 128; off > 0; off >>= 1) {
    if (tid < off) {
      if (bv[tid + off] < bv[tid] || (bv[tid + off] == bv[tid] && bi[tid + off] < bi[tid])) {
        bv[tid] = bv[tid + off]; bi[tid] = bi[tid + off];
      }
    }
    __syncthreads();
  }
  if (tid == 0) out[p] = bi[0];
}

// ---------------- launcher ----------------
extern "C" void kernel_launch(void* const* d_in, const int* in_sizes, int n_in,
                              void* d_out, int out_size, void* d_ws, size_t ws_size,
                              hipStream_t stream) {
  (void)in_sizes; (void)n_in; (void)out_size;
  const float* z = (const float*)d_in[0];
  const float* cb = (const float*)d_in[1];
  int* out = (int*)d_out;

  if (d_ws != nullptr && ws_size >= WS_NEED) {
    char* ws = (char*)d_ws;
    _Float16* B1 = (_Float16*)(ws + OFF_B1);
    _Float16* B2 = (_Float16*)(ws + OFF_B2);
    float* c2 = (float*)(ws + OFF_C2);

    vq_prep_cb<<<KCODES / 4, 256, 0, stream>>>(cb, B1, B2, c2);
    vq_gemm<<<NPTS / 128, 256, 0, stream>>>(
        z, (const unsigned short*)(ws + OFF_B1), (const unsigned short*)(ws + OFF_B2),
        c2, out);
  } else {
    vq_fallback<<<NPTS, 256, 0, stream>>>(z, cb, out);
  }
}